// Round 1
// baseline (766.298 us; speedup 1.0000x reference)
//
#include <hip/hip_runtime.h>
#include <cstdint>
#include <cstddef>

// Problem constants
constexpr int Bc  = 4;
constexpr int Lc  = 1024;
constexpr int Dc  = 1024;
constexpr int Kc  = 8;     // heads
constexpr int Hc  = 64;    // head dim (QK)
constexpr int NHc = 512;   // H*K
constexpr float SCALE = 0.125f;  // 1/sqrt(64)
constexpr long long GSZ = 2LL * Bc * Kc * Lc * Lc;   // graphs elements (both layers)
constexpr long long OSZ = (long long)Bc * Lc * Dc;   // hidden elements per layer

// ---------------------------------------------------------------------------
// Kernel 1: q = relu(hid @ Wq + bq), k = relu(hid @ Wk + bk)
// hid: [4096 x 1024] row-major, W: [1024 x 512] row-major, C: [4096 x 512]
// blockIdx.z: 0 -> q, 1 -> k. Tile 64x64, BK=16, 256 threads, 4x4 microtile.
// ---------------------------------------------------------------------------
__global__ __launch_bounds__(256)
void gemm_qk(const float* __restrict__ A,
             const float* __restrict__ Wq, const float* __restrict__ bq,
             const float* __restrict__ Wk, const float* __restrict__ bk,
             float* __restrict__ qout, float* __restrict__ kout)
{
    const float* W    = blockIdx.z ? Wk : Wq;
    const float* bias = blockIdx.z ? bk : bq;
    float*       C    = blockIdx.z ? kout : qout;

    __shared__ float As[16][66];  // transposed: As[k][m], padded
    __shared__ float Bs[16][64];

    const int tid = threadIdx.x;
    const int m0 = blockIdx.y * 64, n0 = blockIdx.x * 64;
    const int ty = tid >> 4, tx = tid & 15;
    const int ar = tid >> 2, ac = (tid & 3) * 4;   // A tile load coords
    const int br = tid >> 4, bc = (tid & 15) * 4;  // B tile load coords

    float acc[4][4] = {};

    for (int k0 = 0; k0 < Dc; k0 += 16) {
        float4 av = *(const float4*)&A[(size_t)(m0 + ar) * Dc + k0 + ac];
        As[ac + 0][ar] = av.x;
        As[ac + 1][ar] = av.y;
        As[ac + 2][ar] = av.z;
        As[ac + 3][ar] = av.w;
        *(float4*)&Bs[br][bc] = *(const float4*)&W[(size_t)(k0 + br) * NHc + n0 + bc];
        __syncthreads();
        #pragma unroll
        for (int kk = 0; kk < 16; kk++) {
            float a0 = As[kk][ty * 4 + 0], a1 = As[kk][ty * 4 + 1];
            float a2 = As[kk][ty * 4 + 2], a3 = As[kk][ty * 4 + 3];
            float b0 = Bs[kk][tx * 4 + 0], b1 = Bs[kk][tx * 4 + 1];
            float b2 = Bs[kk][tx * 4 + 2], b3 = Bs[kk][tx * 4 + 3];
            acc[0][0] += a0 * b0; acc[0][1] += a0 * b1; acc[0][2] += a0 * b2; acc[0][3] += a0 * b3;
            acc[1][0] += a1 * b0; acc[1][1] += a1 * b1; acc[1][2] += a1 * b2; acc[1][3] += a1 * b3;
            acc[2][0] += a2 * b0; acc[2][1] += a2 * b1; acc[2][2] += a2 * b2; acc[2][3] += a2 * b3;
            acc[3][0] += a3 * b0; acc[3][1] += a3 * b1; acc[3][2] += a3 * b2; acc[3][3] += a3 * b3;
        }
        __syncthreads();
    }

    float4 bv = *(const float4*)&bias[n0 + tx * 4];
    float bb[4] = { bv.x, bv.y, bv.z, bv.w };
    #pragma unroll
    for (int i = 0; i < 4; i++) {
        float4 o;
        o.x = fmaxf(acc[i][0] + bb[0], 0.0f);
        o.y = fmaxf(acc[i][1] + bb[1], 0.0f);
        o.z = fmaxf(acc[i][2] + bb[2], 0.0f);
        o.w = fmaxf(acc[i][3] + bb[3], 0.0f);
        *(float4*)&C[(size_t)(m0 + ty * 4 + i) * NHc + n0 + tx * 4] = o;
    }
}

// ---------------------------------------------------------------------------
// Kernel 2: scores + causal mask + softmax, writes att into graphs region.
// Block: 256 threads, handles 16 q-rows for one (b, head).
// Thread t owns s-columns 4t..4t+3. Causal: valid iff s < q (strict).
// Row 0 (all masked) naturally yields uniform 1/1024, matching jax.
// ---------------------------------------------------------------------------
__global__ __launch_bounds__(256)
void att_softmax(const float* __restrict__ qf, const float* __restrict__ kf,
                 float* __restrict__ att)
{
    __shared__ float qs[16][64];
    __shared__ float red[4][16];

    const int tid = threadIdx.x, lane = tid & 63, wid = tid >> 6;
    const int b = blockIdx.z, kh = blockIdx.y, q0 = blockIdx.x * 16;

    {   // stage 16 q rows (16x64 floats)
        int r = tid >> 4, c = (tid & 15) * 4;
        *(float4*)&qs[r][c] =
            *(const float4*)&qf[((size_t)(b * Lc + q0 + r) * Kc + kh) * Hc + c];
    }
    __syncthreads();

    const int s0 = tid * 4;
    const float* kp = kf + ((size_t)(b * Lc + s0) * Kc + kh) * Hc;  // rows stride 512

    float acc[16][4] = {};
    #pragma unroll 4
    for (int h4 = 0; h4 < 16; h4++) {
        float4 kv0 = *(const float4*)&kp[0    + h4 * 4];
        float4 kv1 = *(const float4*)&kp[512  + h4 * 4];
        float4 kv2 = *(const float4*)&kp[1024 + h4 * 4];
        float4 kv3 = *(const float4*)&kp[1536 + h4 * 4];
        #pragma unroll
        for (int r = 0; r < 16; r++) {
            float4 qv = *(float4*)&qs[r][h4 * 4];
            acc[r][0] += qv.x * kv0.x + qv.y * kv0.y + qv.z * kv0.z + qv.w * kv0.w;
            acc[r][1] += qv.x * kv1.x + qv.y * kv1.y + qv.z * kv1.z + qv.w * kv1.w;
            acc[r][2] += qv.x * kv2.x + qv.y * kv2.y + qv.z * kv2.z + qv.w * kv2.w;
            acc[r][3] += qv.x * kv3.x + qv.y * kv3.y + qv.z * kv3.z + qv.w * kv3.w;
        }
    }

    // scale + causal mask (in place)
    #pragma unroll
    for (int r = 0; r < 16; r++) {
        const int qrow = q0 + r;
        acc[r][0] = (s0 + 0 < qrow) ? acc[r][0] * SCALE : -1e30f;
        acc[r][1] = (s0 + 1 < qrow) ? acc[r][1] * SCALE : -1e30f;
        acc[r][2] = (s0 + 2 < qrow) ? acc[r][2] * SCALE : -1e30f;
        acc[r][3] = (s0 + 3 < qrow) ? acc[r][3] * SCALE : -1e30f;
    }

    // row max (block-wide)
    float rowmax[16];
    #pragma unroll
    for (int r = 0; r < 16; r++) {
        float tm = fmaxf(fmaxf(acc[r][0], acc[r][1]), fmaxf(acc[r][2], acc[r][3]));
        #pragma unroll
        for (int off = 1; off < 64; off <<= 1) tm = fmaxf(tm, __shfl_xor(tm, off));
        if (lane == 0) red[wid][r] = tm;
    }
    __syncthreads();
    #pragma unroll
    for (int r = 0; r < 16; r++)
        rowmax[r] = fmaxf(fmaxf(red[0][r], red[1][r]), fmaxf(red[2][r], red[3][r]));
    __syncthreads();

    // exp + row sum (block-wide)
    float inv[16];
    #pragma unroll
    for (int r = 0; r < 16; r++) {
        acc[r][0] = __expf(acc[r][0] - rowmax[r]);
        acc[r][1] = __expf(acc[r][1] - rowmax[r]);
        acc[r][2] = __expf(acc[r][2] - rowmax[r]);
        acc[r][3] = __expf(acc[r][3] - rowmax[r]);
        float ts = (acc[r][0] + acc[r][1]) + (acc[r][2] + acc[r][3]);
        #pragma unroll
        for (int off = 1; off < 64; off <<= 1) ts += __shfl_xor(ts, off);
        if (lane == 0) red[wid][r] = ts;
    }
    __syncthreads();
    #pragma unroll
    for (int r = 0; r < 16; r++)
        inv[r] = 1.0f / (red[0][r] + red[1][r] + red[2][r] + red[3][r]);

    // write normalized att rows (coalesced float4)
    float* ap = att + ((size_t)(b * Kc + kh) * Lc + q0) * Lc + s0;
    #pragma unroll
    for (int r = 0; r < 16; r++) {
        float4 o = { acc[r][0] * inv[r], acc[r][1] * inv[r],
                     acc[r][2] * inv[r], acc[r][3] * inv[r] };
        *(float4*)&ap[(size_t)r * Lc] = o;
    }
}

// ---------------------------------------------------------------------------
// Kernel 3: out = hid + att @ v   (v = hid column slice per head)
// Per (b, head): M=1024, N=128, K=1024 GEMM. Causality skips s-tiles > q.
// ---------------------------------------------------------------------------
__global__ __launch_bounds__(256)
void pv_residual(const float* __restrict__ attB, const float* __restrict__ hid,
                 float* __restrict__ outp)
{
    __shared__ float As[16][66];
    __shared__ float Bs[16][64];

    const int tid = threadIdx.x;
    const int bkh = blockIdx.z, b = bkh >> 3, kh = bkh & 7;
    const int m0 = blockIdx.y * 64, n0 = blockIdx.x * 64;
    const int ty = tid >> 4, tx = tid & 15;
    const int ar = tid >> 2, ac = (tid & 3) * 4;
    const int br = tid >> 4, bc = (tid & 15) * 4;
    const int vcol = kh * 128 + n0;  // base column of v-slice in hid

    const float* att = attB + (size_t)bkh * Lc * Lc;
    float acc[4][4] = {};

    // rows q in [m0, m0+63]: att[q][s] == 0 for s >= q, EXCEPT q==0 (uniform row)
    const int kmax = (m0 == 0) ? Lc : min(Lc, m0 + 64);

    for (int k0 = 0; k0 < kmax; k0 += 16) {
        float4 av = *(const float4*)&att[(size_t)(m0 + ar) * Lc + k0 + ac];
        As[ac + 0][ar] = av.x;
        As[ac + 1][ar] = av.y;
        As[ac + 2][ar] = av.z;
        As[ac + 3][ar] = av.w;
        *(float4*)&Bs[br][bc] =
            *(const float4*)&hid[(size_t)(b * Lc + k0 + br) * Dc + vcol + bc];
        __syncthreads();
        #pragma unroll
        for (int kk = 0; kk < 16; kk++) {
            float a0 = As[kk][ty * 4 + 0], a1 = As[kk][ty * 4 + 1];
            float a2 = As[kk][ty * 4 + 2], a3 = As[kk][ty * 4 + 3];
            float b0 = Bs[kk][tx * 4 + 0], b1 = Bs[kk][tx * 4 + 1];
            float b2 = Bs[kk][tx * 4 + 2], b3 = Bs[kk][tx * 4 + 3];
            acc[0][0] += a0 * b0; acc[0][1] += a0 * b1; acc[0][2] += a0 * b2; acc[0][3] += a0 * b3;
            acc[1][0] += a1 * b0; acc[1][1] += a1 * b1; acc[1][2] += a1 * b2; acc[1][3] += a1 * b3;
            acc[2][0] += a2 * b0; acc[2][1] += a2 * b1; acc[2][2] += a2 * b2; acc[2][3] += a2 * b3;
            acc[3][0] += a3 * b0; acc[3][1] += a3 * b1; acc[3][2] += a3 * b2; acc[3][3] += a3 * b3;
        }
        __syncthreads();
    }

    #pragma unroll
    for (int i = 0; i < 4; i++) {
        size_t idx = (size_t)(b * Lc + m0 + ty * 4 + i) * Dc + vcol + tx * 4;
        float4 h = *(const float4*)&hid[idx];
        float4 o = { h.x + acc[i][0], h.y + acc[i][1],
                     h.z + acc[i][2], h.w + acc[i][3] };
        *(float4*)&outp[idx] = o;
    }
}

// ---------------------------------------------------------------------------
extern "C" void kernel_launch(void* const* d_in, const int* in_sizes, int n_in,
                              void* d_out, int out_size, void* d_ws, size_t ws_size,
                              hipStream_t stream)
{
    const float* x  = (const float*)d_in[0];
    const float* Wq = (const float*)d_in[1];
    const float* bq = (const float*)d_in[2];
    const float* Wk = (const float*)d_in[3];
    const float* bk = (const float*)d_in[4];
    float* out = (float*)d_out;

    float* qb = (float*)d_ws;                       // [4096 x 512] fp32 (8 MB)
    float* kb = qb + (size_t)Bc * Lc * NHc;         // [4096 x 512] fp32 (8 MB)

    const float* hid = x;
    for (int layer = 0; layer < 2; ++layer) {
        float* attL = out + (size_t)layer * Bc * Kc * Lc * Lc;  // graphs[layer]
        float* outL = out + GSZ + (size_t)layer * OSZ;          // outputs[layer]

        gemm_qk<<<dim3(8, 64, 2), 256, 0, stream>>>(
            hid,
            Wq + (size_t)layer * Dc * NHc, bq + (size_t)layer * NHc,
            Wk + (size_t)layer * Dc * NHc, bk + (size_t)layer * NHc,
            qb, kb);

        att_softmax<<<dim3(64, 8, 4), 256, 0, stream>>>(qb, kb, attL);

        pv_residual<<<dim3(2, 16, 32), 256, 0, stream>>>(attL, hid, outL);

        hid = outL;
    }
}

// Round 4
// 408.631 us; speedup vs baseline: 1.8753x; 1.8753x over previous
//
#include <hip/hip_runtime.h>
#include <cstdint>
#include <cstddef>

typedef float  f32x4  __attribute__((ext_vector_type(4)));
typedef short  bf16x8 __attribute__((ext_vector_type(8)));

constexpr int Bc = 4, Lc = 1024, Dc = 1024, Kc = 8, Hc = 64, NHc = 512;
constexpr float SCALE = 0.125f;                       // 1/sqrt(64)
constexpr long long GSZ = 2LL * Bc * Kc * Lc * Lc;    // graphs elems (both layers)
constexpr long long OSZ = (long long)Bc * Lc * Dc;    // hidden elems per layer

__device__ __forceinline__ unsigned short f2bf(float f) {
    unsigned u = __float_as_uint(f);
    u += 0x7fffu + ((u >> 16) & 1u);   // RNE
    return (unsigned short)(u >> 16);
}

// ---------------------------------------------------------------------------
// cast fp32 -> bf16, 8 elems/thread
// ---------------------------------------------------------------------------
__global__ __launch_bounds__(256)
void cast_bf16(const float* __restrict__ in, unsigned short* __restrict__ outp, int n)
{
    const int i = (blockIdx.x * 256 + threadIdx.x) * 8;
    if (i >= n) return;
    float4 a = *(const float4*)(in + i);
    float4 b = *(const float4*)(in + i + 4);
    bf16x8 v;
    v[0] = (short)f2bf(a.x); v[1] = (short)f2bf(a.y);
    v[2] = (short)f2bf(a.z); v[3] = (short)f2bf(a.w);
    v[4] = (short)f2bf(b.x); v[5] = (short)f2bf(b.y);
    v[6] = (short)f2bf(b.z); v[7] = (short)f2bf(b.w);
    *(bf16x8*)(outp + i) = v;
}

// ---------------------------------------------------------------------------
// K1: q = relu(hid@Wq+bq) bf16, k = relu(hid@Wk+bk) bf16.  MFMA 16x16x32.
// Block 512 thr = 8 waves; block tile 128x128; wave tile 64x32 (4x2 frags).
// A-frags (hid bf16, k-contig) and B-frags (W fp32, n-coalesced) straight
// from global — no LDS.
// ---------------------------------------------------------------------------
__global__ __launch_bounds__(512)
void qk_gemm(const unsigned short* __restrict__ hidb,
             const float* __restrict__ Wq, const float* __restrict__ bq,
             const float* __restrict__ Wk, const float* __restrict__ bk,
             unsigned short* __restrict__ qbuf, unsigned short* __restrict__ kbuf)
{
    const float* W  = blockIdx.z ? Wk : Wq;
    const float* bi = blockIdx.z ? bk : bq;
    unsigned short* C = blockIdx.z ? kbuf : qbuf;
    const int m0 = blockIdx.x * 128, n0 = blockIdx.y * 128;
    const int t = threadIdx.x, lane = t & 63, w = t >> 6;
    const int lr = lane & 15, lg = lane >> 4;
    const int wm = m0 + (w >> 2) * 64;       // wave row base (global)
    const int wn = n0 + (w & 3) * 32;        // wave col base (global)

    f32x4 acc[4][2] = {};
    const unsigned short* Ap = hidb + (size_t)(wm + lr) * Dc + lg * 8;
    const float* Bp = W + (size_t)(lg * 8) * NHc + wn + lr;

    for (int k0 = 0; k0 < Dc; k0 += 32) {
        bf16x8 a[4], bfr[2];
        #pragma unroll
        for (int mi = 0; mi < 4; ++mi)
            a[mi] = *(const bf16x8*)(Ap + (size_t)mi * 16 * Dc + k0);
        #pragma unroll
        for (int ni = 0; ni < 2; ++ni) {
            float tf[8];
            #pragma unroll
            for (int j = 0; j < 8; ++j)
                tf[j] = Bp[(size_t)(k0 + j) * NHc + ni * 16];
            bf16x8 v;
            #pragma unroll
            for (int j = 0; j < 8; ++j) v[j] = (short)f2bf(tf[j]);
            bfr[ni] = v;
        }
        #pragma unroll
        for (int mi = 0; mi < 4; ++mi)
            #pragma unroll
            for (int ni = 0; ni < 2; ++ni)
                acc[mi][ni] = __builtin_amdgcn_mfma_f32_16x16x32_bf16(a[mi], bfr[ni], acc[mi][ni], 0, 0, 0);
    }

    #pragma unroll
    for (int ni = 0; ni < 2; ++ni) {
        const int gc = wn + ni * 16 + lr;
        const float bv = bi[gc];
        #pragma unroll
        for (int mi = 0; mi < 4; ++mi)
            #pragma unroll
            for (int r = 0; r < 4; ++r) {
                const int row = wm + mi * 16 + lg * 4 + r;   // C/D: col=lane&15, row=(lane>>4)*4+r
                float v = fmaxf(acc[mi][ni][r] + bv, 0.0f);
                C[(size_t)row * NHc + gc] = f2bf(v);
            }
    }
}

// ---------------------------------------------------------------------------
// K2: scores (MFMA) + causal mask + softmax, att fp32 -> d_out graphs.
// Block 512 thr = 8 waves, 16 q-rows per block.  Scaled scores strip kept in
// LDS (66 KB); Q/K fragments read straight from global (bf16).
// Causal: valid iff s < q.  Row q==0 -> uniform 1/1024 (matches jax ref).
// ---------------------------------------------------------------------------
__global__ __launch_bounds__(512)
void att_sm(const unsigned short* __restrict__ qbuf, const unsigned short* __restrict__ kbuf,
            float* __restrict__ att)
{
    __shared__ float S[16][1036];
    const int qt = blockIdx.x, kh = blockIdx.y, b = blockIdx.z;
    const int q0 = qt * 16;
    const int t = threadIdx.x, lane = t & 63, w = t >> 6;
    const int lr = lane & 15, lg = lane >> 4;

    bf16x8 aq[2];
    #pragma unroll
    for (int ks = 0; ks < 2; ++ks)
        aq[ks] = *(const bf16x8*)(qbuf + (size_t)(b * Lc + q0 + lr) * NHc + kh * Hc + ks * 32 + lg * 8);

    const int ccount = (q0 + 16 + 63) >> 6;   // 64-col chunks needed (causal)
    for (int c = w; c < ccount; c += 8) {
        f32x4 acc[4] = {};
        #pragma unroll
        for (int ks = 0; ks < 2; ++ks)
            #pragma unroll
            for (int ni = 0; ni < 4; ++ni) {
                const int s = c * 64 + ni * 16 + lr;
                bf16x8 bfr = *(const bf16x8*)(kbuf + (size_t)(b * Lc + s) * NHc + kh * Hc + ks * 32 + lg * 8);
                acc[ni] = __builtin_amdgcn_mfma_f32_16x16x32_bf16(aq[ks], bfr, acc[ni], 0, 0, 0);
            }
        #pragma unroll
        for (int ni = 0; ni < 4; ++ni)
            #pragma unroll
            for (int r = 0; r < 4; ++r)
                S[lg * 4 + r][c * 64 + ni * 16 + lr] = acc[ni][r] * SCALE;
    }
    __syncthreads();

    #pragma unroll
    for (int i = 0; i < 2; ++i) {
        const int row = w * 2 + i, qrow = q0 + row;
        float* orow = att + ((size_t)(b * Kc + kh) * Lc + qrow) * Lc;
        if (qrow == 0) {
            const float u = 1.0f / 1024.0f;
            #pragma unroll
            for (int tt = 0; tt < 4; ++tt) {
                float4 o = { u, u, u, u };
                *(float4*)(orow + lane * 4 + tt * 256) = o;
            }
            continue;
        }
        float p[16];
        float mx = -3.0e38f;
        #pragma unroll
        for (int tt = 0; tt < 4; ++tt) {
            const int col = lane * 4 + tt * 256;
            float4 x = *(const float4*)&S[row][col];
            p[tt*4+0] = x.x; p[tt*4+1] = x.y; p[tt*4+2] = x.z; p[tt*4+3] = x.w;
            if (col + 0 < qrow) mx = fmaxf(mx, x.x);
            if (col + 1 < qrow) mx = fmaxf(mx, x.y);
            if (col + 2 < qrow) mx = fmaxf(mx, x.z);
            if (col + 3 < qrow) mx = fmaxf(mx, x.w);
        }
        #pragma unroll
        for (int off = 1; off < 64; off <<= 1) mx = fmaxf(mx, __shfl_xor(mx, off));
        float sum = 0.0f;
        #pragma unroll
        for (int tt = 0; tt < 4; ++tt)
            #pragma unroll
            for (int j = 0; j < 4; ++j) {
                const int col = lane * 4 + tt * 256 + j;
                const float e = (col < qrow) ? __expf(p[tt*4+j] - mx) : 0.0f;
                p[tt*4+j] = e; sum += e;
            }
        #pragma unroll
        for (int off = 1; off < 64; off <<= 1) sum += __shfl_xor(sum, off);
        const float inv = 1.0f / sum;
        #pragma unroll
        for (int tt = 0; tt < 4; ++tt) {
            float4 o = { p[tt*4+0]*inv, p[tt*4+1]*inv, p[tt*4+2]*inv, p[tt*4+3]*inv };
            *(float4*)(orow + lane * 4 + tt * 256) = o;
        }
    }
}

// ---------------------------------------------------------------------------
// K3: out = res + att @ v  (v = hid bf16 head-slice).  MFMA, causal s-tiles.
// Block 512 thr = 8 waves; tile 128 q x 128 d; wave 64x32.
// att fp32 read from d_out (zeros above diagonal -> full tiles correct),
// converted to bf16 fragments inline.  V^T staged in LDS (padded, conflict-free).
// ---------------------------------------------------------------------------
__global__ __launch_bounds__(512)
void pv_res(const float* __restrict__ att, const unsigned short* __restrict__ hidb,
            const float* __restrict__ res, float* __restrict__ outp)
{
    __shared__ unsigned short Bs[128][72];
    const int mt = blockIdx.x, bh = blockIdx.y;
    const int b = bh >> 3, kh = bh & 7;
    const int m0 = mt * 128;
    const int t = threadIdx.x, lane = t & 63, w = t >> 6;
    const int lr = lane & 15, lg = lane >> 4;
    const int wm = (w >> 2) * 64, wn = (w & 3) * 32;
    const float* attB = att + (size_t)bh * Lc * Lc;

    f32x4 acc[4][2] = {};
    const int ntiles = mt ? (2 * mt + 2) : 16;   // causal; row 0 is uniform -> full
    const int ss = t & 63, dg = t >> 6;

    for (int ti = 0; ti < ntiles; ++ti) {
        const int s0 = ti * 64;
        {   // stage V^T tile: Bs[d][s], d 0..127, s 0..63
            const unsigned short* vp = hidb + (size_t)(b * Lc + s0 + ss) * Dc + kh * 128 + dg * 16;
            bf16x8 v0 = *(const bf16x8*)(vp);
            bf16x8 v1 = *(const bf16x8*)(vp + 8);
            #pragma unroll
            for (int j = 0; j < 8; ++j) Bs[dg * 16 + j][ss] = (unsigned short)v0[j];
            #pragma unroll
            for (int j = 0; j < 8; ++j) Bs[dg * 16 + 8 + j][ss] = (unsigned short)v1[j];
        }
        __syncthreads();
        #pragma unroll
        for (int ks = 0; ks < 2; ++ks) {
            bf16x8 a[4];
            #pragma unroll
            for (int mi = 0; mi < 4; ++mi) {
                const float* ap = attB + (size_t)(m0 + wm + mi * 16 + lr) * Lc + s0 + ks * 32 + lg * 8;
                float4 x0 = *(const float4*)ap;
                float4 x1 = *(const float4*)(ap + 4);
                bf16x8 v;
                v[0] = (short)f2bf(x0.x); v[1] = (short)f2bf(x0.y);
                v[2] = (short)f2bf(x0.z); v[3] = (short)f2bf(x0.w);
                v[4] = (short)f2bf(x1.x); v[5] = (short)f2bf(x1.y);
                v[6] = (short)f2bf(x1.z); v[7] = (short)f2bf(x1.w);
                a[mi] = v;
            }
            #pragma unroll
            for (int ni = 0; ni < 2; ++ni) {
                bf16x8 bb = *(const bf16x8*)&Bs[wn + ni * 16 + lr][ks * 32 + lg * 8];
                #pragma unroll
                for (int mi = 0; mi < 4; ++mi)
                    acc[mi][ni] = __builtin_amdgcn_mfma_f32_16x16x32_bf16(a[mi], bb, acc[mi][ni], 0, 0, 0);
            }
        }
        __syncthreads();
    }

    #pragma unroll
    for (int ni = 0; ni < 2; ++ni) {
        const int gc = kh * 128 + wn + ni * 16 + lr;
        #pragma unroll
        for (int mi = 0; mi < 4; ++mi)
            #pragma unroll
            for (int r = 0; r < 4; ++r) {
                const size_t idx = (size_t)(b * Lc + m0 + wm + mi * 16 + lg * 4 + r) * Dc + gc;
                outp[idx] = res[idx] + acc[mi][ni][r];
            }
    }
}

// ---------------------------------------------------------------------------
extern "C" void kernel_launch(void* const* d_in, const int* in_sizes, int n_in,
                              void* d_out, int out_size, void* d_ws, size_t ws_size,
                              hipStream_t stream)
{
    const float* x  = (const float*)d_in[0];
    const float* Wq = (const float*)d_in[1];
    const float* bq = (const float*)d_in[2];
    const float* Wk = (const float*)d_in[3];
    const float* bk = (const float*)d_in[4];
    float* out = (float*)d_out;

    unsigned short* hidb = (unsigned short*)d_ws;              // [4096][1024] bf16
    unsigned short* qb   = hidb + (size_t)Bc * Lc * Dc;        // [4096][512]  bf16
    unsigned short* kb   = qb   + (size_t)Bc * Lc * NHc;       // [4096][512]  bf16

    const int nhid = Bc * Lc * Dc;   // 4194304
    cast_bf16<<<nhid / 8 / 256, 256, 0, stream>>>(x, hidb, nhid);

    for (int l = 0; l < 2; ++l) {
        float* attL = out + (size_t)l * (GSZ / 2);
        float* outL = out + GSZ + (size_t)l * OSZ;
        const float* resL = l ? (out + GSZ) : x;

        qk_gemm<<<dim3(32, 4, 2), 512, 0, stream>>>(
            hidb, Wq + (size_t)l * Dc * NHc, bq + l * NHc,
                  Wk + (size_t)l * Dc * NHc, bk + l * NHc, qb, kb);

        att_sm<<<dim3(64, 8, 4), 512, 0, stream>>>(qb, kb, attL);

        pv_res<<<dim3(8, 32), 512, 0, stream>>>(attL, hidb, resL, outL);

        if (l == 0)
            cast_bf16<<<nhid / 8 / 256, 256, 0, stream>>>(outL, hidb, nhid);
    }
}

// Round 5
// 268.947 us; speedup vs baseline: 2.8493x; 1.5194x over previous
//
#include <hip/hip_runtime.h>
#include <cstdint>
#include <cstddef>

typedef float  f32x4  __attribute__((ext_vector_type(4)));
typedef short  bf16x8 __attribute__((ext_vector_type(8)));

constexpr int Bc = 4, Lc = 1024, Dc = 1024, Kc = 8, Hc = 64, NHc = 512;
constexpr float SCALE = 0.125f;                       // 1/sqrt(64)
constexpr long long GSZ = 2LL * Bc * Kc * Lc * Lc;    // graphs elems (both layers)
constexpr long long OSZ = (long long)Bc * Lc * Dc;    // hidden elems per layer

__device__ __forceinline__ unsigned short f2bf(float f) {
    unsigned u = __float_as_uint(f);
    u += 0x7fffu + ((u >> 16) & 1u);   // RNE
    return (unsigned short)(u >> 16);
}

// ---------------------------------------------------------------------------
// cast fp32 -> bf16, 8 elems/thread
// ---------------------------------------------------------------------------
__global__ __launch_bounds__(256)
void cast_bf16(const float* __restrict__ in, unsigned short* __restrict__ outp, int n)
{
    const int i = (blockIdx.x * 256 + threadIdx.x) * 8;
    if (i >= n) return;
    float4 a = *(const float4*)(in + i);
    float4 b = *(const float4*)(in + i + 4);
    bf16x8 v;
    v[0] = (short)f2bf(a.x); v[1] = (short)f2bf(a.y);
    v[2] = (short)f2bf(a.z); v[3] = (short)f2bf(a.w);
    v[4] = (short)f2bf(b.x); v[5] = (short)f2bf(b.y);
    v[6] = (short)f2bf(b.z); v[7] = (short)f2bf(b.w);
    *(bf16x8*)(outp + i) = v;
}

// ---------------------------------------------------------------------------
// K0: W [1024 k][512 n] fp32  ->  Wt [512 n][1024 k] bf16 (per layer, per q/k).
// Wt parked in the (not yet written) att-graph region of d_out.
// z: 0..3 -> layer = z>>1, mat = z&1 (0=q,1=k). Tile 64x64 via LDS.
// ---------------------------------------------------------------------------
__global__ __launch_bounds__(256)
void wtrans(const float* __restrict__ Wq, const float* __restrict__ Wk,
            float* __restrict__ outbase)
{
    __shared__ float Tl[64][68];
    const int z = blockIdx.z, layer = z >> 1, m = z & 1;
    const float* src = (m ? Wk : Wq) + (size_t)layer * Dc * NHc;
    unsigned short* dst = (unsigned short*)(outbase + (size_t)layer * (GSZ / 2))
                          + (size_t)m * NHc * Dc;
    const int k0 = blockIdx.x * 64, n0 = blockIdx.y * 64;
    const int t = threadIdx.x;

    {   // load 64k x 64n tile, coalesced
        const int r0 = t >> 4, c0 = (t & 15) * 4;
        #pragma unroll
        for (int i = 0; i < 4; ++i)
            *(float4*)&Tl[r0 + 16 * i][c0] =
                *(const float4*)&src[(size_t)(k0 + r0 + 16 * i) * NHc + n0 + c0];
    }
    __syncthreads();
    {   // write transposed, bf16, k-contiguous
        const int nn = t >> 2, ks = (t & 3) * 16;
        bf16x8 v0, v1;
        #pragma unroll
        for (int j = 0; j < 8; ++j) v0[j] = (short)f2bf(Tl[ks + j][nn]);
        #pragma unroll
        for (int j = 0; j < 8; ++j) v1[j] = (short)f2bf(Tl[ks + 8 + j][nn]);
        unsigned short* dp = dst + (size_t)(n0 + nn) * Dc + k0 + ks;
        *(bf16x8*)dp       = v0;
        *(bf16x8*)(dp + 8) = v1;
    }
}

// ---------------------------------------------------------------------------
// K1: q = relu(hid@Wq+bq) bf16, k = relu(hid@Wk+bk) bf16.  MFMA 16x16x32.
// Block 512 thr = 8 waves; tile 128x128; wave 64x32 (4x2 frags).
// A-frags (hidb) and B-frags (Wt, n-major bf16) are single b128 global loads.
// ---------------------------------------------------------------------------
__global__ __launch_bounds__(512)
void qk_gemm(const unsigned short* __restrict__ hidb,
             const unsigned short* __restrict__ Wtq, const unsigned short* __restrict__ Wtk,
             const float* __restrict__ bq, const float* __restrict__ bk,
             unsigned short* __restrict__ qbuf, unsigned short* __restrict__ kbuf)
{
    const unsigned short* Wt = blockIdx.z ? Wtk : Wtq;
    const float* bi = blockIdx.z ? bk : bq;
    unsigned short* C = blockIdx.z ? kbuf : qbuf;
    const int m0 = blockIdx.x * 128, n0 = blockIdx.y * 128;
    const int t = threadIdx.x, lane = t & 63, w = t >> 6;
    const int lr = lane & 15, lg = lane >> 4;
    const int wm = m0 + (w >> 2) * 64;       // wave row base
    const int wn = n0 + (w & 3) * 32;        // wave col base

    f32x4 acc[4][2] = {};
    const unsigned short* Ap = hidb + (size_t)(wm + lr) * Dc + lg * 8;
    const unsigned short* Bp = Wt + (size_t)(wn + lr) * Dc + lg * 8;

    for (int k0 = 0; k0 < Dc; k0 += 32) {
        bf16x8 a[4], bfr[2];
        #pragma unroll
        for (int mi = 0; mi < 4; ++mi)
            a[mi] = *(const bf16x8*)(Ap + (size_t)mi * 16 * Dc + k0);
        #pragma unroll
        for (int ni = 0; ni < 2; ++ni)
            bfr[ni] = *(const bf16x8*)(Bp + (size_t)ni * 16 * Dc + k0);
        #pragma unroll
        for (int mi = 0; mi < 4; ++mi)
            #pragma unroll
            for (int ni = 0; ni < 2; ++ni)
                acc[mi][ni] = __builtin_amdgcn_mfma_f32_16x16x32_bf16(a[mi], bfr[ni], acc[mi][ni], 0, 0, 0);
    }

    #pragma unroll
    for (int ni = 0; ni < 2; ++ni) {
        const int gc = wn + ni * 16 + lr;
        const float bv = bi[gc];
        #pragma unroll
        for (int mi = 0; mi < 4; ++mi)
            #pragma unroll
            for (int r = 0; r < 4; ++r) {
                const int row = wm + mi * 16 + lg * 4 + r;   // C/D: col=lane&15, row=(lane>>4)*4+r
                float v = fmaxf(acc[mi][ni][r] + bv, 0.0f);
                C[(size_t)row * NHc + gc] = f2bf(v);
            }
    }
}

// ---------------------------------------------------------------------------
// K2 (fused): scores -> softmax -> att write -> PV -> residual, per 16 q-rows.
// Block 512 thr = 8 waves, one (b, head, q-tile).  Normalized P kept in the
// LDS strip S and consumed directly by the PV MFMAs (V read from L2-resident
// hidb).  Only 2 barriers per block; PV phase is barrier-free.
// Causal: valid iff s < q.  Row q==0 -> uniform 1/1024 (matches jax ref).
// ---------------------------------------------------------------------------
__global__ __launch_bounds__(512)
void attn_fused(const unsigned short* __restrict__ qbuf,
                const unsigned short* __restrict__ kbuf,
                const unsigned short* __restrict__ hidb,
                const float* __restrict__ res,
                float* __restrict__ att, float* __restrict__ outp)
{
    __shared__ float S[16][1036];
    const int qt = blockIdx.x, kh = blockIdx.y, b = blockIdx.z;
    const int q0 = qt * 16;
    const int t = threadIdx.x, lane = t & 63, w = t >> 6;
    const int lr = lane & 15, lg = lane >> 4;

    // ---- phase 1: scaled scores into S (causal chunks only) ----
    bf16x8 aq[2];
    #pragma unroll
    for (int ks = 0; ks < 2; ++ks)
        aq[ks] = *(const bf16x8*)(qbuf + (size_t)(b * Lc + q0 + lr) * NHc + kh * Hc + ks * 32 + lg * 8);

    const int ccount = (q0 + 16 + 63) >> 6;   // 64-col chunks needed
    for (int c = w; c < ccount; c += 8) {
        f32x4 acc[4] = {};
        #pragma unroll
        for (int ks = 0; ks < 2; ++ks)
            #pragma unroll
            for (int ni = 0; ni < 4; ++ni) {
                const int s = c * 64 + ni * 16 + lr;
                bf16x8 bfr = *(const bf16x8*)(kbuf + (size_t)(b * Lc + s) * NHc + kh * Hc + ks * 32 + lg * 8);
                acc[ni] = __builtin_amdgcn_mfma_f32_16x16x32_bf16(aq[ks], bfr, acc[ni], 0, 0, 0);
            }
        #pragma unroll
        for (int ni = 0; ni < 4; ++ni)
            #pragma unroll
            for (int r = 0; r < 4; ++r)
                S[lg * 4 + r][c * 64 + ni * 16 + lr] = acc[ni][r] * SCALE;
    }
    __syncthreads();

    // ---- phase 2: softmax; store normalized P back to S (full row, zeros in
    //      masked cols) and write att to global ----
    #pragma unroll
    for (int i = 0; i < 2; ++i) {
        const int row = w * 2 + i, qrow = q0 + row;
        float* orow = att + ((size_t)(b * Kc + kh) * Lc + qrow) * Lc;
        if (qrow == 0) {
            const float u = 1.0f / 1024.0f;
            #pragma unroll
            for (int tt = 0; tt < 4; ++tt) {
                float4 o = { u, u, u, u };
                const int col = lane * 4 + tt * 256;
                *(float4*)&S[row][col] = o;
                *(float4*)(orow + col) = o;
            }
            continue;
        }
        float p[16];
        float mx = -3.0e38f;
        #pragma unroll
        for (int tt = 0; tt < 4; ++tt) {
            const int col = lane * 4 + tt * 256;
            float4 x = *(const float4*)&S[row][col];
            p[tt*4+0] = x.x; p[tt*4+1] = x.y; p[tt*4+2] = x.z; p[tt*4+3] = x.w;
            if (col + 0 < qrow) mx = fmaxf(mx, x.x);
            if (col + 1 < qrow) mx = fmaxf(mx, x.y);
            if (col + 2 < qrow) mx = fmaxf(mx, x.z);
            if (col + 3 < qrow) mx = fmaxf(mx, x.w);
        }
        #pragma unroll
        for (int off = 1; off < 64; off <<= 1) mx = fmaxf(mx, __shfl_xor(mx, off));
        float sum = 0.0f;
        #pragma unroll
        for (int tt = 0; tt < 4; ++tt)
            #pragma unroll
            for (int j = 0; j < 4; ++j) {
                const int col = lane * 4 + tt * 256 + j;
                const float e = (col < qrow) ? __expf(p[tt*4+j] - mx) : 0.0f;
                p[tt*4+j] = e; sum += e;
            }
        #pragma unroll
        for (int off = 1; off < 64; off <<= 1) sum += __shfl_xor(sum, off);
        const float inv = 1.0f / sum;
        #pragma unroll
        for (int tt = 0; tt < 4; ++tt) {
            const int col = lane * 4 + tt * 256;
            float4 o = { p[tt*4+0]*inv, p[tt*4+1]*inv, p[tt*4+2]*inv, p[tt*4+3]*inv };
            *(float4*)&S[row][col] = o;
            *(float4*)(orow + col) = o;
        }
    }
    __syncthreads();

    // ---- phase 3: PV (+residual).  Wave w owns d-cols [w*16, w*16+16). ----
    const int stiles = (qt == 0) ? 16 : ccount;   // row 0 is a full uniform row
    f32x4 acc = {};
    const int dcol = kh * 128 + w * 16 + lr;      // this lane's V column
    for (int ti = 0; ti < stiles; ++ti) {
        const int s0 = ti * 64;
        #pragma unroll
        for (int ks = 0; ks < 2; ++ks) {
            const float* ap = &S[lr][s0 + ks * 32 + lg * 8];
            float4 x0 = *(const float4*)ap;
            float4 x1 = *(const float4*)(ap + 4);
            bf16x8 a;
            a[0] = (short)f2bf(x0.x); a[1] = (short)f2bf(x0.y);
            a[2] = (short)f2bf(x0.z); a[3] = (short)f2bf(x0.w);
            a[4] = (short)f2bf(x1.x); a[5] = (short)f2bf(x1.y);
            a[6] = (short)f2bf(x1.z); a[7] = (short)f2bf(x1.w);
            bf16x8 bb;
            const unsigned short* vp = hidb + (size_t)(b * Lc + s0 + ks * 32 + lg * 8) * Dc + dcol;
            #pragma unroll
            for (int j = 0; j < 8; ++j) bb[j] = (short)vp[(size_t)j * Dc];
            acc = __builtin_amdgcn_mfma_f32_16x16x32_bf16(a, bb, acc, 0, 0, 0);
        }
    }
    #pragma unroll
    for (int r = 0; r < 4; ++r) {
        const size_t idx = (size_t)(b * Lc + q0 + lg * 4 + r) * Dc + dcol;
        outp[idx] = res[idx] + acc[r];
    }
}

// ---------------------------------------------------------------------------
extern "C" void kernel_launch(void* const* d_in, const int* in_sizes, int n_in,
                              void* d_out, int out_size, void* d_ws, size_t ws_size,
                              hipStream_t stream)
{
    const float* x  = (const float*)d_in[0];
    const float* Wq = (const float*)d_in[1];
    const float* bq = (const float*)d_in[2];
    const float* Wk = (const float*)d_in[3];
    const float* bk = (const float*)d_in[4];
    float* out = (float*)d_out;

    unsigned short* hidb = (unsigned short*)d_ws;              // [4096][1024] bf16
    unsigned short* qb   = hidb + (size_t)Bc * Lc * Dc;        // [4096][512]  bf16
    unsigned short* kb   = qb   + (size_t)Bc * Lc * NHc;       // [4096][512]  bf16

    const int nhid = Bc * Lc * Dc;   // 4194304
    cast_bf16<<<nhid / 8 / 256, 256, 0, stream>>>(x, hidb, nhid);

    // both layers' Wt parked at the start of each layer's att-graph region;
    // consumed by qk_gemm, then overwritten by attn_fused.
    wtrans<<<dim3(16, 8, 4), 256, 0, stream>>>(Wq, Wk, out);

    for (int l = 0; l < 2; ++l) {
        float* attL = out + (size_t)l * (GSZ / 2);
        float* outL = out + GSZ + (size_t)l * OSZ;
        const float* resL = l ? (out + GSZ) : x;
        const unsigned short* WtL = (const unsigned short*)attL;

        qk_gemm<<<dim3(32, 4, 2), 512, 0, stream>>>(
            hidb, WtL, WtL + (size_t)NHc * Dc, bq + l * NHc, bk + l * NHc, qb, kb);

        attn_fused<<<dim3(64, 8, 4), 512, 0, stream>>>(qb, kb, hidb, resL, attL, outL);

        if (l == 0)
            cast_bf16<<<nhid / 8 / 256, 256, 0, stream>>>(outL, hidb, nhid);
    }
}